// Round 1
// baseline (254.448 us; speedup 1.0000x reference)
//
#include <hip/hip_runtime.h>

typedef unsigned short u16;
typedef __attribute__((ext_vector_type(8))) __bf16 bf16x8;
typedef __attribute__((ext_vector_type(4))) float f32x4;

__device__ inline u16 f2bf(float f) {
  unsigned u = __builtin_bit_cast(unsigned, f);
  u += 0x7FFFu + ((u >> 16) & 1u);
  return (u16)(u >> 16);
}

__device__ inline void async16(const void* g, void* l) {
  __builtin_amdgcn_global_load_lds((const __attribute__((address_space(1))) void*)g,
                                   (__attribute__((address_space(3))) void*)l, 16, 0, 0);
}

// ---------------- x fp32 -> bf16 ----------------
__global__ __launch_bounds__(256) void xconv(const float* __restrict__ x, u16* __restrict__ xb) {
  int i = blockIdx.x * 256 + threadIdx.x;
  float4 v = ((const float4*)x)[i];
  ushort4 r;
  r.x = f2bf(v.x); r.y = f2bf(v.y); r.z = f2bf(v.z); r.w = f2bf(v.w);
  ((ushort4*)xb)[i] = r;
}

// ---------------- W (d,e) fp32 -> Wt (e,d) bf16 ----------------
__global__ __launch_bounds__(256) void wtrans(const float* __restrict__ W, u16* __restrict__ Wt) {
  __shared__ u16 tile[32][33];
  const int e0 = blockIdx.x * 32;
  const int d0 = blockIdx.y * 32;
  const int tx = threadIdx.x & 31;
  const int ty = threadIdx.x >> 5; // 0..7
#pragma unroll
  for (int i = ty; i < 32; i += 8)
    tile[i][tx] = f2bf(W[(size_t)(d0 + i) * 1024 + e0 + tx]);
  __syncthreads();
#pragma unroll
  for (int i = ty; i < 32; i += 8)
    Wt[(size_t)(e0 + i) * 1024 + d0 + tx] = tile[tx][i];
}

// ---------------- GEMM C[M,N] = A[M,K] * Bt[N,K]^T  (m97 structure) ----------------
template <int OUT_BF16>
__global__ __launch_bounds__(256) void gemm_bt(const u16* __restrict__ A,
                                               const u16* __restrict__ Bt,
                                               void* __restrict__ Cp,
                                               int M, int N, int K) {
  __shared__ __align__(16) u16 As[128 * 32];
  __shared__ __align__(16) u16 Bs[128 * 32];
  const int tid = threadIdx.x;
  const int lane = tid & 63;
  const int wave = tid >> 6;
  const int lr = lane & 15;
  const int lk = (lane >> 4) * 8;
  const int wm = (wave >> 1) * 64;
  const int wn = (wave & 1) * 64;
  const int bm = blockIdx.x * 128;
  const int bn = blockIdx.y * 128;
  const int srow = lane >> 2;        // 0..15 within chunk
  const int scol = (lane & 3) * 8;

  f32x4 acc[4][4] = {};

  for (int k0 = 0; k0 < K; k0 += 32) {
#pragma unroll
    for (int r = 0; r < 2; ++r) {
      const int chunk = r * 4 + wave;
      const int row = chunk * 16 + srow;
      async16(A + (size_t)(bm + row) * K + k0 + scol, &As[chunk * 512 + lane * 8]);
      async16(Bt + (size_t)(bn + row) * K + k0 + scol, &Bs[chunk * 512 + lane * 8]);
    }
    __syncthreads();
    bf16x8 a[4], b[4];
#pragma unroll
    for (int i = 0; i < 4; ++i) {
      a[i] = *(const bf16x8*)&As[(wm + i * 16 + lr) * 32 + lk];
      b[i] = *(const bf16x8*)&Bs[(wn + i * 16 + lr) * 32 + lk];
    }
#pragma unroll
    for (int mi = 0; mi < 4; ++mi)
#pragma unroll
      for (int ni = 0; ni < 4; ++ni)
        acc[mi][ni] = __builtin_amdgcn_mfma_f32_16x16x32_bf16(a[mi], b[ni], acc[mi][ni], 0, 0, 0);
    __syncthreads();
  }

#pragma unroll
  for (int mi = 0; mi < 4; ++mi) {
#pragma unroll
    for (int ni = 0; ni < 4; ++ni) {
      const int col = bn + wn + ni * 16 + lr;
#pragma unroll
      for (int j = 0; j < 4; ++j) {
        const int row = bm + wm + mi * 16 + (lane >> 4) * 4 + j;
        if (OUT_BF16)
          ((u16*)Cp)[(size_t)row * N + col] = f2bf(acc[mi][ni][j]);
        else
          ((float*)Cp)[(size_t)row * N + col] = acc[mi][ni][j];
      }
    }
  }
}

// ---------------- Flash causal attention ----------------
// QKV: (4096 rows) x 3072 bf16; row = b*2048+s; Q at col h*64+d, K at 1024+h*64+d, V at 2048+h*64+d
// Obuf: (4096) x 1024 bf16, col = h*64+d
__global__ __launch_bounds__(256) void attn_kernel(const u16* __restrict__ QKV, u16* __restrict__ Obuf) {
  constexpr int S = 2048, LD = 3072;
  __shared__ __align__(16) u16 Ks[64 * 64];
  __shared__ __align__(16) u16 Vt[64 * 64];
  __shared__ __align__(16) u16 Ps[4][16 * 64];

  const int qt = blockIdx.x;       // 0..31
  const int bh = blockIdx.y;       // 0..31
  const int b = bh >> 4, h = bh & 15;
  const int tid = threadIdx.x, lane = tid & 63, wave = tid >> 6;
  const int lr = lane & 15, lg = lane >> 4;

  // Q fragments (wave owns 16 q rows)
  const int qrow = qt * 64 + wave * 16 + lr;
  const u16* qptr = QKV + (size_t)(b * S + qrow) * LD + h * 64;
  bf16x8 qf0 = *(const bf16x8*)(qptr + lg * 8);
  bf16x8 qf1 = *(const bf16x8*)(qptr + 32 + lg * 8);

  f32x4 o[4] = {};
  float m_run[4] = {-1e30f, -1e30f, -1e30f, -1e30f};
  float l_run[4] = {0.f, 0.f, 0.f, 0.f};

  const int sn = tid >> 2;          // 0..63  (kv row within tile)
  const int sd = (tid & 3) * 16;    // d offset

  for (int kt = 0; kt <= qt; ++kt) {
    __syncthreads();
    // stage K row-major, V transposed
    const u16* kg = QKV + (size_t)(b * S + kt * 64 + sn) * LD + 1024 + h * 64 + sd;
    const u16* vg = kg + 1024;
    uint4 k0v = *(const uint4*)kg;
    uint4 k1v = *(const uint4*)(kg + 8);
    uint4 v0v = *(const uint4*)vg;
    uint4 v1v = *(const uint4*)(vg + 8);
    *(uint4*)&Ks[sn * 64 + sd] = k0v;
    *(uint4*)&Ks[sn * 64 + sd + 8] = k1v;
    u16 vtmp[16];
    *(uint4*)&vtmp[0] = v0v;
    *(uint4*)&vtmp[8] = v1v;
#pragma unroll
    for (int i = 0; i < 16; ++i) Vt[(sd + i) * 64 + sn] = vtmp[i];
    __syncthreads();

    // S = Q K^T / 8
    f32x4 sfr[4];
#pragma unroll
    for (int fi = 0; fi < 4; ++fi) {
      bf16x8 kb0 = *(const bf16x8*)&Ks[(fi * 16 + lr) * 64 + lg * 8];
      bf16x8 kb1 = *(const bf16x8*)&Ks[(fi * 16 + lr) * 64 + 32 + lg * 8];
      f32x4 s = {};
      s = __builtin_amdgcn_mfma_f32_16x16x32_bf16(qf0, kb0, s, 0, 0, 0);
      s = __builtin_amdgcn_mfma_f32_16x16x32_bf16(qf1, kb1, s, 0, 0, 0);
      sfr[fi] = s * 0.125f;
    }
    if (kt == qt) {
#pragma unroll
      for (int fi = 0; fi < 4; ++fi) {
        const int kabs = kt * 64 + fi * 16 + lr;
#pragma unroll
        for (int j = 0; j < 4; ++j) {
          const int qabs = qt * 64 + wave * 16 + lg * 4 + j;
          if (kabs > qabs) sfr[fi][j] = -1e30f;
        }
      }
    }
    float mx[4], scl[4], rs[4], pv[4][4];
#pragma unroll
    for (int j = 0; j < 4; ++j) {
      mx[j] = fmaxf(fmaxf(sfr[0][j], sfr[1][j]), fmaxf(sfr[2][j], sfr[3][j]));
      mx[j] = fmaxf(mx[j], __shfl_xor(mx[j], 1));
      mx[j] = fmaxf(mx[j], __shfl_xor(mx[j], 2));
      mx[j] = fmaxf(mx[j], __shfl_xor(mx[j], 4));
      mx[j] = fmaxf(mx[j], __shfl_xor(mx[j], 8));
      const float mnew = fmaxf(m_run[j], mx[j]);
      scl[j] = __expf(m_run[j] - mnew);
      m_run[j] = mnew;
    }
#pragma unroll
    for (int fi = 0; fi < 4; ++fi)
#pragma unroll
      for (int j = 0; j < 4; ++j)
        pv[fi][j] = __expf(sfr[fi][j] - m_run[j]);
#pragma unroll
    for (int j = 0; j < 4; ++j) {
      rs[j] = pv[0][j] + pv[1][j] + pv[2][j] + pv[3][j];
      rs[j] += __shfl_xor(rs[j], 1);
      rs[j] += __shfl_xor(rs[j], 2);
      rs[j] += __shfl_xor(rs[j], 4);
      rs[j] += __shfl_xor(rs[j], 8);
      l_run[j] = l_run[j] * scl[j] + rs[j];
    }
#pragma unroll
    for (int fi = 0; fi < 4; ++fi)
#pragma unroll
      for (int j = 0; j < 4; ++j) {
        o[fi][j] *= scl[j];
        Ps[wave][(lg * 4 + j) * 64 + fi * 16 + lr] = f2bf(pv[fi][j]);
      }
    asm volatile("s_waitcnt lgkmcnt(0)" ::: "memory");
    // O += P V
#pragma unroll
    for (int kk = 0; kk < 2; ++kk) {
      bf16x8 pa = *(const bf16x8*)&Ps[wave][lr * 64 + kk * 32 + lg * 8];
#pragma unroll
      for (int fi = 0; fi < 4; ++fi) {
        bf16x8 vb = *(const bf16x8*)&Vt[(fi * 16 + lr) * 64 + kk * 32 + lg * 8];
        o[fi] = __builtin_amdgcn_mfma_f32_16x16x32_bf16(pa, vb, o[fi], 0, 0, 0);
      }
    }
  }

#pragma unroll
  for (int fi = 0; fi < 4; ++fi) {
#pragma unroll
    for (int j = 0; j < 4; ++j) {
      const int row = b * S + qt * 64 + wave * 16 + lg * 4 + j;
      const int col = h * 64 + fi * 16 + lr;
      Obuf[(size_t)row * 1024 + col] = f2bf(o[fi][j] / l_run[j]);
    }
  }
}

extern "C" void kernel_launch(void* const* d_in, const int* in_sizes, int n_in,
                              void* d_out, int out_size, void* d_ws, size_t ws_size,
                              hipStream_t stream) {
  const float* x  = (const float*)d_in[0];
  const float* WQ = (const float*)d_in[1];
  const float* WK = (const float*)d_in[2];
  const float* WV = (const float*)d_in[3];
  const float* WO = (const float*)d_in[4];
  float* out = (float*)d_out;

  u16* xb    = (u16*)d_ws;                      // 4096*1024
  u16* WtQKV = xb + (size_t)4096 * 1024;        // 3072*1024
  u16* WtO   = WtQKV + (size_t)3072 * 1024;     // 1024*1024
  u16* QKV   = WtO + (size_t)1024 * 1024;       // 4096*3072
  u16* Obuf  = QKV + (size_t)4096 * 3072;       // 4096*1024

  xconv<<<4096, 256, 0, stream>>>(x, xb);
  wtrans<<<dim3(32, 32), 256, 0, stream>>>(WQ, WtQKV);
  wtrans<<<dim3(32, 32), 256, 0, stream>>>(WK, WtQKV + (size_t)1024 * 1024);
  wtrans<<<dim3(32, 32), 256, 0, stream>>>(WV, WtQKV + (size_t)2048 * 1024);
  wtrans<<<dim3(32, 32), 256, 0, stream>>>(WO, WtO);

  gemm_bt<1><<<dim3(32, 24), 256, 0, stream>>>(xb, WtQKV, QKV, 4096, 3072, 1024);
  attn_kernel<<<dim3(32, 32), 256, 0, stream>>>(QKV, Obuf);
  gemm_bt<0><<<dim3(32, 8), 256, 0, stream>>>(Obuf, WtO, out, 4096, 1024, 1024);
}

// Round 2
// 211.195 us; speedup vs baseline: 1.2048x; 1.2048x over previous
//
#include <hip/hip_runtime.h>

typedef unsigned short u16;
typedef __attribute__((ext_vector_type(8))) __bf16 bf16x8;
typedef __attribute__((ext_vector_type(4))) float f32x4;

__device__ inline u16 f2bf(float f) {
  unsigned u = __builtin_bit_cast(unsigned, f);
  u += 0x7FFFu + ((u >> 16) & 1u);
  return (u16)(u >> 16);
}

__device__ inline void async16(const void* g, void* l) {
  __builtin_amdgcn_global_load_lds((const __attribute__((address_space(1))) void*)g,
                                   (__attribute__((address_space(3))) void*)l, 16, 0, 0);
}

// ---------------- x fp32 -> bf16 ----------------
__global__ __launch_bounds__(256) void xconv(const float* __restrict__ x, u16* __restrict__ xb) {
  int i = blockIdx.x * 256 + threadIdx.x;
  float4 v = ((const float4*)x)[i];
  ushort4 r;
  r.x = f2bf(v.x); r.y = f2bf(v.y); r.z = f2bf(v.z); r.w = f2bf(v.w);
  ((ushort4*)xb)[i] = r;
}

// ---------------- W (d,e) fp32 -> Wt (e,d) bf16 ----------------
__global__ __launch_bounds__(256) void wtrans(const float* __restrict__ W, u16* __restrict__ Wt) {
  __shared__ u16 tile[32][33];
  const int e0 = blockIdx.x * 32;
  const int d0 = blockIdx.y * 32;
  const int tx = threadIdx.x & 31;
  const int ty = threadIdx.x >> 5;
#pragma unroll
  for (int i = ty; i < 32; i += 8)
    tile[i][tx] = f2bf(W[(size_t)(d0 + i) * 1024 + e0 + tx]);
  __syncthreads();
#pragma unroll
  for (int i = ty; i < 32; i += 8)
    Wt[(size_t)(e0 + i) * 1024 + d0 + tx] = tile[tx][i];
}

// ---------------- V slice of QKV -> Vtg[b*1024+dg][s] (transposed) ----------------
__global__ __launch_bounds__(256) void vtrans(const u16* __restrict__ QKV, u16* __restrict__ Vtg) {
  __shared__ u16 t[32][66];
  const int tid = threadIdx.x;
  const int s0 = blockIdx.x * 32, dg0 = blockIdx.y * 64, b = blockIdx.z;
  {
    const int i = tid >> 3, c = (tid & 7) * 8;
    uint4 v = *(const uint4*)(QKV + (size_t)(b * 2048 + s0 + i) * 3072 + 2048 + dg0 + c);
    u16 tmp[8];
    *(uint4*)tmp = v;
#pragma unroll
    for (int e = 0; e < 8; ++e) t[i][c + e] = tmp[e];
  }
  __syncthreads();
  {
    const int r = tid >> 2, cg = (tid & 3) * 8;
    u16 tmp[8];
#pragma unroll
    for (int e = 0; e < 8; ++e) tmp[e] = t[cg + e][r];
    *(uint4*)(Vtg + (size_t)(b * 1024 + dg0 + r) * 2048 + s0 + cg) = *(uint4*)tmp;
  }
}

// ---------------- GEMM C[M,N] = A[M,K] * Bt[N,K]^T  (m97 structure) ----------------
template <int OUT_BF16>
__global__ __launch_bounds__(256) void gemm_bt(const u16* __restrict__ A,
                                               const u16* __restrict__ Bt,
                                               void* __restrict__ Cp,
                                               int M, int N, int K) {
  __shared__ __align__(16) u16 As[128 * 32];
  __shared__ __align__(16) u16 Bs[128 * 32];
  const int tid = threadIdx.x;
  const int lane = tid & 63;
  const int wave = tid >> 6;
  const int lr = lane & 15;
  const int lk = (lane >> 4) * 8;
  const int wm = (wave >> 1) * 64;
  const int wn = (wave & 1) * 64;
  const int bm = blockIdx.x * 128;
  const int bn = blockIdx.y * 128;
  const int srow = lane >> 2;
  const int scol = (lane & 3) * 8;

  f32x4 acc[4][4] = {};

  for (int k0 = 0; k0 < K; k0 += 32) {
#pragma unroll
    for (int r = 0; r < 2; ++r) {
      const int chunk = r * 4 + wave;
      const int row = chunk * 16 + srow;
      async16(A + (size_t)(bm + row) * K + k0 + scol, &As[chunk * 512 + lane * 8]);
      async16(Bt + (size_t)(bn + row) * K + k0 + scol, &Bs[chunk * 512 + lane * 8]);
    }
    __syncthreads();
    bf16x8 a[4], b[4];
#pragma unroll
    for (int i = 0; i < 4; ++i) {
      a[i] = *(const bf16x8*)&As[(wm + i * 16 + lr) * 32 + lk];
      b[i] = *(const bf16x8*)&Bs[(wn + i * 16 + lr) * 32 + lk];
    }
#pragma unroll
    for (int mi = 0; mi < 4; ++mi)
#pragma unroll
      for (int ni = 0; ni < 4; ++ni)
        acc[mi][ni] = __builtin_amdgcn_mfma_f32_16x16x32_bf16(a[mi], b[ni], acc[mi][ni], 0, 0, 0);
    __syncthreads();
  }

#pragma unroll
  for (int mi = 0; mi < 4; ++mi) {
#pragma unroll
    for (int ni = 0; ni < 4; ++ni) {
      const int col = bn + wn + ni * 16 + lr;
#pragma unroll
      for (int j = 0; j < 4; ++j) {
        const int row = bm + wm + mi * 16 + (lane >> 4) * 4 + j;
        if (OUT_BF16)
          ((u16*)Cp)[(size_t)row * N + col] = f2bf(acc[mi][ni][j]);
        else
          ((float*)Cp)[(size_t)row * N + col] = acc[mi][ni][j];
      }
    }
  }
}

// ---------------- Flash causal attention (dbuf + async stage + XOR swizzle) ----------------
// QKV: (4096)x3072 bf16; Q at col h*64+d, K at 1024+h*64+d
// Vtg: [b*1024 + h*64 + d][s]  (V transposed per head)
// Obuf: (4096)x1024 bf16
__global__ __launch_bounds__(256) void attn_kernel(const u16* __restrict__ QKV,
                                                   const u16* __restrict__ Vtg,
                                                   u16* __restrict__ Obuf) {
  constexpr int S = 2048, LD = 3072;
  __shared__ __align__(16) u16 Ks[2][64 * 64];
  __shared__ __align__(16) u16 Vs[2][64 * 64];
  __shared__ __align__(16) u16 Ps[4][16 * 64];

  const int qt = blockIdx.x;
  const int bh = blockIdx.y;
  const int b = bh >> 4, h = bh & 15;
  const int tid = threadIdx.x, lane = tid & 63, wave = tid >> 6;
  const int lr = lane & 15, lg = lane >> 4;

  const int qrow = qt * 64 + wave * 16 + lr;
  const u16* qptr = QKV + (size_t)(b * S + qrow) * LD + h * 64;
  const bf16x8 qf0 = *(const bf16x8*)(qptr + lg * 8);
  const bf16x8 qf1 = *(const bf16x8*)(qptr + 32 + lg * 8);

  // staging: 512 16B-chunks per 64x64 tile, 2 per thread; pre-swizzled global source (rule #21)
  const int c0 = tid, c1 = tid + 256;
  const int r0 = c0 >> 3, x0 = ((c0 & 7) ^ (r0 & 7)) << 3;
  const int r1 = c1 >> 3, x1 = ((c1 & 7) ^ (r1 & 7)) << 3;
  const u16* Kbase = QKV + (size_t)b * S * LD + 1024 + h * 64;
  const u16* Vbase = Vtg + (size_t)bh * 64 * 2048;

  f32x4 o[4] = {};
  float m_run[4] = {-1e30f, -1e30f, -1e30f, -1e30f};
  float l_run[4] = {0.f, 0.f, 0.f, 0.f};

  // prologue: stage kt=0 into buf 0
  async16(Kbase + (size_t)r0 * LD + x0, &Ks[0][c0 * 8]);
  async16(Kbase + (size_t)r1 * LD + x1, &Ks[0][c1 * 8]);
  async16(Vbase + (size_t)r0 * 2048 + x0, &Vs[0][c0 * 8]);
  async16(Vbase + (size_t)r1 * 2048 + x1, &Vs[0][c1 * 8]);
  __syncthreads();

  int cur = 0;
  for (int kt = 0; kt <= qt; ++kt) {
    // prefetch next tile into other buffer (overlaps with compute below)
    if (kt < qt) {
      const int nk = kt + 1;
      async16(Kbase + (size_t)(nk * 64 + r0) * LD + x0, &Ks[cur ^ 1][c0 * 8]);
      async16(Kbase + (size_t)(nk * 64 + r1) * LD + x1, &Ks[cur ^ 1][c1 * 8]);
      async16(Vbase + (size_t)r0 * 2048 + nk * 64 + x0, &Vs[cur ^ 1][c0 * 8]);
      async16(Vbase + (size_t)r1 * 2048 + nk * 64 + x1, &Vs[cur ^ 1][c1 * 8]);
    }
    const u16* ks = Ks[cur];
    const u16* vs = Vs[cur];

    // S = Q K^T / 8   (swizzled reads: 2-way max -> free per m136)
    f32x4 sfr[4];
    __builtin_amdgcn_s_setprio(1);
#pragma unroll
    for (int fi = 0; fi < 4; ++fi) {
      const int row = fi * 16 + lr;
      const bf16x8 kb0 = *(const bf16x8*)&ks[row * 64 + ((lg ^ (row & 7)) << 3)];
      const bf16x8 kb1 = *(const bf16x8*)&ks[row * 64 + (((4 + lg) ^ (row & 7)) << 3)];
      f32x4 s = {};
      s = __builtin_amdgcn_mfma_f32_16x16x32_bf16(qf0, kb0, s, 0, 0, 0);
      s = __builtin_amdgcn_mfma_f32_16x16x32_bf16(qf1, kb1, s, 0, 0, 0);
      sfr[fi] = s * 0.125f;
    }
    __builtin_amdgcn_s_setprio(0);

    if (kt == qt) {
#pragma unroll
      for (int fi = 0; fi < 4; ++fi) {
        const int kabs = fi * 16 + lr;
#pragma unroll
        for (int j = 0; j < 4; ++j) {
          const int qabs = wave * 16 + lg * 4 + j;
          if (kabs > qabs) sfr[fi][j] = -1e30f;
        }
      }
    }

    float mx[4], scl[4], rs[4], pv[4][4];
#pragma unroll
    for (int j = 0; j < 4; ++j) {
      mx[j] = fmaxf(fmaxf(sfr[0][j], sfr[1][j]), fmaxf(sfr[2][j], sfr[3][j]));
      mx[j] = fmaxf(mx[j], __shfl_xor(mx[j], 1));
      mx[j] = fmaxf(mx[j], __shfl_xor(mx[j], 2));
      mx[j] = fmaxf(mx[j], __shfl_xor(mx[j], 4));
      mx[j] = fmaxf(mx[j], __shfl_xor(mx[j], 8));
      const float mnew = fmaxf(m_run[j], mx[j]);
      scl[j] = __expf(m_run[j] - mnew);
      m_run[j] = mnew;
    }
#pragma unroll
    for (int fi = 0; fi < 4; ++fi)
#pragma unroll
      for (int j = 0; j < 4; ++j)
        pv[fi][j] = __expf(sfr[fi][j] - m_run[j]);
#pragma unroll
    for (int j = 0; j < 4; ++j) {
      rs[j] = pv[0][j] + pv[1][j] + pv[2][j] + pv[3][j];
      rs[j] += __shfl_xor(rs[j], 1);
      rs[j] += __shfl_xor(rs[j], 2);
      rs[j] += __shfl_xor(rs[j], 4);
      rs[j] += __shfl_xor(rs[j], 8);
      l_run[j] = l_run[j] * scl[j] + rs[j];
    }
    // P -> LDS (swizzled write), rescale O
#pragma unroll
    for (int fi = 0; fi < 4; ++fi) {
      const int cc = fi * 2 + (lr >> 3);
#pragma unroll
      for (int j = 0; j < 4; ++j) {
        o[fi][j] *= scl[j];
        const int row = lg * 4 + j;
        Ps[wave][row * 64 + ((cc ^ (row & 7)) << 3) + (lr & 7)] = f2bf(pv[fi][j]);
      }
    }
    asm volatile("s_waitcnt lgkmcnt(0)" ::: "memory");
    __builtin_amdgcn_sched_barrier(0);

    // O += P V  (A = P from LDS, B = V^T rows, both swizzled)
    __builtin_amdgcn_s_setprio(1);
#pragma unroll
    for (int kk = 0; kk < 2; ++kk) {
      const bf16x8 pa = *(const bf16x8*)&Ps[wave][lr * 64 + (((kk * 4 + lg) ^ (lr & 7)) << 3)];
#pragma unroll
      for (int fi = 0; fi < 4; ++fi) {
        const int vrow = fi * 16 + lr;
        const bf16x8 vb = *(const bf16x8*)&vs[vrow * 64 + (((kk * 4 + lg) ^ (vrow & 7)) << 3)];
        o[fi] = __builtin_amdgcn_mfma_f32_16x16x32_bf16(pa, vb, o[fi], 0, 0, 0);
      }
    }
    __builtin_amdgcn_s_setprio(0);
    __syncthreads();
    cur ^= 1;
  }

#pragma unroll
  for (int j = 0; j < 4; ++j) {
    const float inv = 1.0f / l_run[j];
    const int row = b * S + qt * 64 + wave * 16 + lg * 4 + j;
#pragma unroll
    for (int fi = 0; fi < 4; ++fi) {
      const int col = h * 64 + fi * 16 + lr;
      Obuf[(size_t)row * 1024 + col] = f2bf(o[fi][j] * inv);
    }
  }
}

extern "C" void kernel_launch(void* const* d_in, const int* in_sizes, int n_in,
                              void* d_out, int out_size, void* d_ws, size_t ws_size,
                              hipStream_t stream) {
  const float* x  = (const float*)d_in[0];
  const float* WQ = (const float*)d_in[1];
  const float* WK = (const float*)d_in[2];
  const float* WV = (const float*)d_in[3];
  const float* WO = (const float*)d_in[4];
  float* out = (float*)d_out;

  u16* xb    = (u16*)d_ws;                      // 4096*1024
  u16* WtQKV = xb + (size_t)4096 * 1024;        // 3072*1024
  u16* WtO   = WtQKV + (size_t)3072 * 1024;     // 1024*1024
  u16* QKV   = WtO + (size_t)1024 * 1024;       // 4096*3072
  u16* Obuf  = QKV + (size_t)4096 * 3072;       // 4096*1024
  u16* Vtg   = Obuf + (size_t)4096 * 1024;      // 2048*2048

  xconv<<<4096, 256, 0, stream>>>(x, xb);
  wtrans<<<dim3(32, 32), 256, 0, stream>>>(WQ, WtQKV);
  wtrans<<<dim3(32, 32), 256, 0, stream>>>(WK, WtQKV + (size_t)1024 * 1024);
  wtrans<<<dim3(32, 32), 256, 0, stream>>>(WV, WtQKV + (size_t)2048 * 1024);
  wtrans<<<dim3(32, 32), 256, 0, stream>>>(WO, WtO);

  gemm_bt<1><<<dim3(32, 24), 256, 0, stream>>>(xb, WtQKV, QKV, 4096, 3072, 1024);
  vtrans<<<dim3(64, 16, 2), 256, 0, stream>>>(QKV, Vtg);
  attn_kernel<<<dim3(32, 32), 256, 0, stream>>>(QKV, Vtg, Obuf);
  gemm_bt<0><<<dim3(32, 8), 256, 0, stream>>>(Obuf, WtO, out, 4096, 1024, 1024);
}

// Round 3
// 164.917 us; speedup vs baseline: 1.5429x; 1.2806x over previous
//
#include <hip/hip_runtime.h>

typedef unsigned short u16;
typedef unsigned int u32;
typedef __attribute__((ext_vector_type(8))) __bf16 bf16x8;
typedef __attribute__((ext_vector_type(2))) __bf16 bf16x2;
typedef __attribute__((ext_vector_type(4))) float f32x4;
typedef __attribute__((ext_vector_type(16))) float f32x16;
typedef __attribute__((ext_vector_type(4))) u32 u32x4;

__device__ inline u16 f2bf(float f) {
  unsigned u = __builtin_bit_cast(unsigned, f);
  u += 0x7FFFu + ((u >> 16) & 1u);
  return (u16)(u >> 16);
}

__device__ inline u32 packbf(float a, float b) {
  bf16x2 t;
  t[0] = (__bf16)a;
  t[1] = (__bf16)b;
  return __builtin_bit_cast(u32, t);
}

__device__ inline void async16(const void* g, void* l) {
  __builtin_amdgcn_global_load_lds((const __attribute__((address_space(1))) void*)g,
                                   (__attribute__((address_space(3))) void*)l, 16, 0, 0);
}

// ---------------- x fp32 -> bf16 ----------------
__global__ __launch_bounds__(256) void xconv(const float* __restrict__ x, u16* __restrict__ xb) {
  int i = blockIdx.x * 256 + threadIdx.x;
  float4 v = ((const float4*)x)[i];
  ushort4 r;
  r.x = f2bf(v.x); r.y = f2bf(v.y); r.z = f2bf(v.z); r.w = f2bf(v.w);
  ((ushort4*)xb)[i] = r;
}

// ---------------- W (d,e) fp32 -> Wt (e,d) bf16 ----------------
__global__ __launch_bounds__(256) void wtrans(const float* __restrict__ W, u16* __restrict__ Wt) {
  __shared__ u16 tile[32][33];
  const int e0 = blockIdx.x * 32;
  const int d0 = blockIdx.y * 32;
  const int tx = threadIdx.x & 31;
  const int ty = threadIdx.x >> 5;
#pragma unroll
  for (int i = ty; i < 32; i += 8)
    tile[i][tx] = f2bf(W[(size_t)(d0 + i) * 1024 + e0 + tx]);
  __syncthreads();
#pragma unroll
  for (int i = ty; i < 32; i += 8)
    Wt[(size_t)(e0 + i) * 1024 + d0 + tx] = tile[tx][i];
}

// ---------------- V slice of QKV -> Vtg[b*1024+dg][s] (transposed) ----------------
__global__ __launch_bounds__(256) void vtrans(const u16* __restrict__ QKV, u16* __restrict__ Vtg) {
  __shared__ u16 t[32][66];
  const int tid = threadIdx.x;
  const int s0 = blockIdx.x * 32, dg0 = blockIdx.y * 64, b = blockIdx.z;
  {
    const int i = tid >> 3, c = (tid & 7) * 8;
    uint4 v = *(const uint4*)(QKV + (size_t)(b * 2048 + s0 + i) * 3072 + 2048 + dg0 + c);
    u16 tmp[8];
    *(uint4*)tmp = v;
#pragma unroll
    for (int e = 0; e < 8; ++e) t[i][c + e] = tmp[e];
  }
  __syncthreads();
  {
    const int r = tid >> 2, cg = (tid & 3) * 8;
    u16 tmp[8];
#pragma unroll
    for (int e = 0; e < 8; ++e) tmp[e] = t[cg + e][r];
    *(uint4*)(Vtg + (size_t)(b * 1024 + dg0 + r) * 2048 + s0 + cg) = *(uint4*)tmp;
  }
}

// ---------------- GEMM C[M,N] = A[M,K] * Bt[N,K]^T  (m97 structure) ----------------
template <int OUT_BF16>
__global__ __launch_bounds__(256) void gemm_bt(const u16* __restrict__ A,
                                               const u16* __restrict__ Bt,
                                               void* __restrict__ Cp,
                                               int M, int N, int K) {
  __shared__ __align__(16) u16 As[128 * 32];
  __shared__ __align__(16) u16 Bs[128 * 32];
  const int tid = threadIdx.x;
  const int lane = tid & 63;
  const int wave = tid >> 6;
  const int lr = lane & 15;
  const int lk = (lane >> 4) * 8;
  const int wm = (wave >> 1) * 64;
  const int wn = (wave & 1) * 64;
  const int bm = blockIdx.x * 128;
  const int bn = blockIdx.y * 128;
  const int srow = lane >> 2;
  const int scol = (lane & 3) * 8;

  f32x4 acc[4][4] = {};

  for (int k0 = 0; k0 < K; k0 += 32) {
#pragma unroll
    for (int r = 0; r < 2; ++r) {
      const int chunk = r * 4 + wave;
      const int row = chunk * 16 + srow;
      async16(A + (size_t)(bm + row) * K + k0 + scol, &As[chunk * 512 + lane * 8]);
      async16(Bt + (size_t)(bn + row) * K + k0 + scol, &Bs[chunk * 512 + lane * 8]);
    }
    __syncthreads();
    bf16x8 a[4], b[4];
#pragma unroll
    for (int i = 0; i < 4; ++i) {
      a[i] = *(const bf16x8*)&As[(wm + i * 16 + lr) * 32 + lk];
      b[i] = *(const bf16x8*)&Bs[(wn + i * 16 + lr) * 32 + lk];
    }
#pragma unroll
    for (int mi = 0; mi < 4; ++mi)
#pragma unroll
      for (int ni = 0; ni < 4; ++ni)
        acc[mi][ni] = __builtin_amdgcn_mfma_f32_16x16x32_bf16(a[mi], b[ni], acc[mi][ni], 0, 0, 0);
    __syncthreads();
  }

#pragma unroll
  for (int mi = 0; mi < 4; ++mi) {
#pragma unroll
    for (int ni = 0; ni < 4; ++ni) {
      const int col = bn + wn + ni * 16 + lr;
#pragma unroll
      for (int j = 0; j < 4; ++j) {
        const int row = bm + wm + mi * 16 + (lane >> 4) * 4 + j;
        if (OUT_BF16)
          ((u16*)Cp)[(size_t)row * N + col] = f2bf(acc[mi][ni][j]);
        else
          ((float*)Cp)[(size_t)row * N + col] = acc[mi][ni][j];
      }
    }
  }
}

// ---------------- Flash causal attention: 32x32 swapped-QK^T, in-register softmax ----------------
// QKV: (4096)x3072 bf16; Q at col h*64+d, K at 1024+h*64+d
// Vtg: [bh*64 + d][s]  (V transposed per head)
// Obuf: (4096)x1024 bf16
// Wave owns 32 q-rows (q = qbase + lane&31). Lane holds P^T: k rows in regs,
// so softmax row-reduce = in-lane chain + one xor-32 swap (m214 structure).
__global__ __launch_bounds__(256) void attn_kernel(const u16* __restrict__ QKV,
                                                   const u16* __restrict__ Vtg,
                                                   u16* __restrict__ Obuf) {
  constexpr int S = 2048, LD = 3072;
  __shared__ __align__(16) u16 Ks[2][64 * 64];
  __shared__ __align__(16) u16 Vs[2][64 * 64];

  const int qt = 15 - blockIdx.x;   // longest blocks dispatched first
  const int bh = blockIdx.y;
  const int b = bh >> 4, h = bh & 15;
  const int tid = threadIdx.x, lane = tid & 63, wave = tid >> 6;
  const int l31 = lane & 31, lh = lane >> 5;

  const int qbase = qt * 128 + wave * 32;

  // Q fragments: lane holds Q[q=qbase+l31][d = c*16 + lh*8 + i]  (B-operand layout)
  const u16* qrow = QKV + (size_t)(b * S + qbase + l31) * LD + h * 64;
  bf16x8 qf[4];
#pragma unroll
  for (int c = 0; c < 4; ++c) qf[c] = *(const bf16x8*)(qrow + c * 16 + lh * 8);

  // staging: 512 16B chunks per 64x64 tile, 2/thread, pre-swizzled source (rule #21)
  const int c0 = tid, c1 = tid + 256;
  const int r0 = c0 >> 3, x0 = ((c0 & 7) ^ (r0 & 7)) << 3;
  const int r1 = c1 >> 3, x1 = ((c1 & 7) ^ (r1 & 7)) << 3;
  const u16* Kbase = QKV + (size_t)b * S * LD + 1024 + h * 64;
  const u16* Vbase = Vtg + (size_t)bh * 64 * 2048;

#define STAGE(buf, kt_)                                                          \
  do {                                                                           \
    async16(Kbase + (size_t)((kt_)*64 + r0) * LD + x0, &Ks[buf][c0 * 8]);        \
    async16(Kbase + (size_t)((kt_)*64 + r1) * LD + x1, &Ks[buf][c1 * 8]);        \
    async16(Vbase + (size_t)r0 * 2048 + (kt_)*64 + x0, &Vs[buf][c0 * 8]);        \
    async16(Vbase + (size_t)r1 * 2048 + (kt_)*64 + x1, &Vs[buf][c1 * 8]);        \
  } while (0)

  f32x16 o0 = {}, o1 = {};
  float m_run = -1e30f, l_run = 0.f;
  const float c1s = 0.18033688011112042f;  // 0.125 * log2(e): softmax in exp2 domain

  const int nkt = 2 * qt + 2;       // tiles staged by the block
  const int ktlast = qbase >> 6;    // this wave's last (diagonal) tile

  STAGE(0, 0);
  __syncthreads();

  int cur = 0;
  for (int kt = 0; kt < nkt; ++kt) {
    if (kt + 1 < nkt) STAGE(cur ^ 1, kt + 1);

    if (kt <= ktlast) {
      const u16* ks = Ks[cur];
      const u16* vs = Vs[cur];

      // S^T = K Q^T : lane -> (q = l31, k rows in regs)
      f32x16 t0 = {}, t1 = {};
      __builtin_amdgcn_s_setprio(1);
#pragma unroll
      for (int c = 0; c < 4; ++c) {
        const int cc = 2 * c + lh;
        const bf16x8 kf0 = *(const bf16x8*)&ks[l31 * 64 + ((cc ^ (l31 & 7)) << 3)];
        const bf16x8 kf1 = *(const bf16x8*)&ks[(32 + l31) * 64 + ((cc ^ (l31 & 7)) << 3)];
        t0 = __builtin_amdgcn_mfma_f32_32x32x16_bf16(kf0, qf[c], t0, 0, 0, 0);
        t1 = __builtin_amdgcn_mfma_f32_32x32x16_bf16(kf1, qf[c], t1, 0, 0, 0);
      }
      __builtin_amdgcn_s_setprio(0);

      // scale into exp2 domain
#pragma unroll
      for (int r = 0; r < 16; ++r) { t0[r] *= c1s; t1[r] *= c1s; }

      // causal mask (exactly one masked tile per wave)
      if (kt == ktlast) {
        const int kb = kt * 64 + 4 * lh;
        const int qa = qbase + l31;
#pragma unroll
        for (int r = 0; r < 16; ++r) {
          const int ko = (r & 3) + 8 * (r >> 2);
          if (kb + ko > qa) t0[r] = -3e38f;
          if (kb + 32 + ko > qa) t1[r] = -3e38f;
        }
      }

      // row max: in-lane chain + one lane-half swap
      float mx = fmaxf(t0[0], t1[0]);
#pragma unroll
      for (int r = 1; r < 16; ++r) mx = fmaxf(mx, fmaxf(t0[r], t1[r]));
      mx = fmaxf(mx, __shfl_xor(mx, 32));

      // T13 defer-max: only rescale when max grew past threshold
      if (__any(mx > m_run + 8.0f)) {
        const float mnew = fmaxf(m_run, mx);
        const float scl = exp2f(m_run - mnew);
        m_run = mnew;
        l_run *= scl;
#pragma unroll
        for (int r = 0; r < 16; ++r) {
          const float sq = __shfl(scl, ((r & 3) + 8 * (r >> 2)) + 4 * lh);
          o0[r] *= sq;
          o1[r] *= sq;
        }
      }

      // exp + row sum (reuse t regs as P)
      float ls = 0.f;
#pragma unroll
      for (int r = 0; r < 16; ++r) {
        t0[r] = exp2f(t0[r] - m_run);
        t1[r] = exp2f(t1[r] - m_run);
        ls += t0[r] + t1[r];
      }
      ls += __shfl_xor(ls, 32);
      l_run += ls;

      // pack P to bf16 pairs; swap halves once to build PV A-fragments (T12 idea)
      u32 pk0[8], pk1[8], sw0[8], sw1[8];
#pragma unroll
      for (int j = 0; j < 8; ++j) {
        pk0[j] = packbf(t0[2 * j], t0[2 * j + 1]);
        pk1[j] = packbf(t1[2 * j], t1[2 * j + 1]);
      }
#pragma unroll
      for (int j = 0; j < 8; ++j) {
        sw0[j] = __shfl_xor(pk0[j], 32);
        sw1[j] = __shfl_xor(pk1[j], 32);
      }

      // O += P V : A = P[q][k-chunk], B = Vt rows (d) x k cols
      __builtin_amdgcn_s_setprio(1);
#pragma unroll
      for (int kc = 0; kc < 4; ++kc) {
        const u32* pk = (kc >> 1) ? pk1 : pk0;
        const u32* sw = (kc >> 1) ? sw1 : sw0;
        const int q4 = (kc & 1) * 4;
        u32x4 wv;
        wv[0] = lh ? sw[q4 + 2] : pk[q4 + 0];
        wv[1] = lh ? sw[q4 + 3] : pk[q4 + 1];
        wv[2] = lh ? pk[q4 + 2] : sw[q4 + 0];
        wv[3] = lh ? pk[q4 + 3] : sw[q4 + 1];
        const bf16x8 pa = __builtin_bit_cast(bf16x8, wv);
        const int cc = 2 * kc + lh;
        const bf16x8 vf0 = *(const bf16x8*)&vs[l31 * 64 + ((cc ^ (l31 & 7)) << 3)];
        const bf16x8 vf1 = *(const bf16x8*)&vs[(32 + l31) * 64 + ((cc ^ (l31 & 7)) << 3)];
        o0 = __builtin_amdgcn_mfma_f32_32x32x16_bf16(pa, vf0, o0, 0, 0, 0);
        o1 = __builtin_amdgcn_mfma_f32_32x32x16_bf16(pa, vf1, o1, 0, 0, 0);
      }
      __builtin_amdgcn_s_setprio(0);
    }

    __syncthreads();
    cur ^= 1;
  }
#undef STAGE

  // epilogue: normalize and store (lane holds O[q-rows in regs][d = dc*32 + l31])
  const float linv = 1.0f / l_run;
#pragma unroll
  for (int r = 0; r < 16; ++r) {
    const int qo = (r & 3) + 8 * (r >> 2) + 4 * lh;
    const float lq = __shfl(linv, qo);
    u16* op = Obuf + (size_t)(b * S + qbase + qo) * 1024 + h * 64 + l31;
    op[0] = f2bf(o0[r] * lq);
    op[32] = f2bf(o1[r] * lq);
  }
}

extern "C" void kernel_launch(void* const* d_in, const int* in_sizes, int n_in,
                              void* d_out, int out_size, void* d_ws, size_t ws_size,
                              hipStream_t stream) {
  const float* x  = (const float*)d_in[0];
  const float* WQ = (const float*)d_in[1];
  const float* WK = (const float*)d_in[2];
  const float* WV = (const float*)d_in[3];
  const float* WO = (const float*)d_in[4];
  float* out = (float*)d_out;

  u16* xb    = (u16*)d_ws;                      // 4096*1024
  u16* WtQKV = xb + (size_t)4096 * 1024;        // 3072*1024
  u16* WtO   = WtQKV + (size_t)3072 * 1024;     // 1024*1024
  u16* QKV   = WtO + (size_t)1024 * 1024;       // 4096*3072
  u16* Obuf  = QKV + (size_t)4096 * 3072;       // 4096*1024
  u16* Vtg   = Obuf + (size_t)4096 * 1024;      // 2048*2048

  xconv<<<4096, 256, 0, stream>>>(x, xb);
  wtrans<<<dim3(32, 32), 256, 0, stream>>>(WQ, WtQKV);
  wtrans<<<dim3(32, 32), 256, 0, stream>>>(WK, WtQKV + (size_t)1024 * 1024);
  wtrans<<<dim3(32, 32), 256, 0, stream>>>(WV, WtQKV + (size_t)2048 * 1024);
  wtrans<<<dim3(32, 32), 256, 0, stream>>>(WO, WtO);

  gemm_bt<1><<<dim3(32, 24), 256, 0, stream>>>(xb, WtQKV, QKV, 4096, 3072, 1024);
  vtrans<<<dim3(64, 16, 2), 256, 0, stream>>>(QKV, Vtg);
  attn_kernel<<<dim3(16, 32), 256, 0, stream>>>(QKV, Vtg, Obuf);
  gemm_bt<0><<<dim3(32, 8), 256, 0, stream>>>(Obuf, WtO, out, 4096, 1024, 1024);
}